// Round 1
// baseline (1431.757 us; speedup 1.0000x reference)
//
#include <hip/hip_runtime.h>
#include <math.h>

#define BSZ 16
#define NQ  900
#define NCL 92
#define NT  256
#define SUMT (BSZ*NT)   /* 4096 */
#define MM  NQ          /* JV columns (queries) */
#define NN  NT          /* JV rows (targets)    */

// ---------------------------------------------------------------------------
// Kernel 1: cost matrix. One block per (b,q); 256 threads sweep 4096 targets.
// Also scatters the per-image diagonal block transposed into costT[tgt][query]
// so the LSA scan reads coalesced rows.
// ---------------------------------------------------------------------------
__global__ __launch_bounds__(256) void cost_kernel(
    const float* __restrict__ logits,
    const float* __restrict__ boxes,
    const int*   __restrict__ labels,
    const float* __restrict__ tbox,
    float* __restrict__ C,
    float* __restrict__ costT) {
#pragma clang fp contract(off)
  const int bq  = blockIdx.x;
  const int b   = bq / NQ;
  const int tid = threadIdx.x;

  __shared__ float lg[NCL];
  __shared__ float red[128];

  if (tid < NCL) lg[tid] = logits[(size_t)bq * NCL + tid];
  __syncthreads();

  // softmax over 92 classes (max-subtracted, fp32)
  if (tid < 128) red[tid] = (tid < NCL) ? lg[tid] : -INFINITY;
  __syncthreads();
  for (int s = 64; s > 0; s >>= 1) {
    if (tid < s) red[tid] = fmaxf(red[tid], red[tid + s]);
    __syncthreads();
  }
  const float mx = red[0];
  __syncthreads();
  float e = 0.f;
  if (tid < NCL) e = expf(lg[tid] - mx);
  if (tid < 128) red[tid] = e;
  __syncthreads();
  for (int s = 64; s > 0; s >>= 1) {
    if (tid < s) red[tid] += red[tid + s];
    __syncthreads();
  }
  const float sm = red[0];
  __syncthreads();
  if (tid < NCL) lg[tid] = e / sm;
  __syncthreads();

  // predicted box (broadcast load)
  const float cx = boxes[(size_t)bq*4 + 0];
  const float cy = boxes[(size_t)bq*4 + 1];
  const float w  = boxes[(size_t)bq*4 + 2];
  const float h  = boxes[(size_t)bq*4 + 3];
  const float bx1 = cx - 0.5f*w, by1 = cy - 0.5f*h;
  const float bx2 = cx + 0.5f*w, by2 = cy + 0.5f*h;
  const float area1 = (bx2 - bx1) * (by2 - by1);

  const int q = bq - b * NQ;
  for (int jt = tid; jt < SUMT; jt += 256) {
    const float4 tb = ((const float4*)tbox)[jt];
    const int lab = labels[jt];
    const float cc = -lg[lab];                               // cost_class
    const float d0 = fabsf(cx - tb.x), d1 = fabsf(cy - tb.y);
    const float d2 = fabsf(w - tb.z),  d3 = fabsf(h - tb.w);
    const float cb = ((d0 + d1) + d2) + d3;                  // cost_bbox (L1 on cxcywh)
    const float tx1 = tb.x - 0.5f*tb.z, ty1 = tb.y - 0.5f*tb.w;
    const float tx2 = tb.x + 0.5f*tb.z, ty2 = tb.y + 0.5f*tb.w;
    const float area2 = (tx2 - tx1) * (ty2 - ty1);
    const float ltx = fmaxf(bx1, tx1), lty = fmaxf(by1, ty1);
    const float rbx = fminf(bx2, tx2), rby = fminf(by2, ty2);
    const float iw = fmaxf(rbx - ltx, 0.f), ih = fmaxf(rby - lty, 0.f);
    const float inter = iw * ih;
    const float uni = (area1 + area2) - inter;
    const float iou = inter / uni;
    const float ex1 = fminf(bx1, tx1), ey1 = fminf(by1, ty1);
    const float ex2 = fmaxf(bx2, tx2), ey2 = fmaxf(by2, ty2);
    const float ew = fmaxf(ex2 - ex1, 0.f), eh = fmaxf(ey2 - ey1, 0.f);
    const float ea = ew * eh;
    const float giou = iou - (ea - uni) / ea;
    const float cval = (5.0f*cb + 1.0f*cc) + 2.0f*(-giou);
    C[(size_t)bq * SUMT + jt] = cval;
    if (costT && (jt >> 8) == b) costT[(size_t)jt * MM + q] = cval;  // transposed slab
  }
}

// ---------------------------------------------------------------------------
// Kernel 2: Jonker-Volgenant LSA, one block (256 threads) per image.
// Faithful float64 replication of the reference lsa() (post-transpose:
// n=256 targets, m=900 queries), incl. first-index argmin tie-break.
// ---------------------------------------------------------------------------
__global__ __launch_bounds__(256) void lsa_kernel(
    const float* __restrict__ C,
    const float* __restrict__ costT,   // may be null -> strided C fallback
    float* __restrict__ rows_out,
    float* __restrict__ cols_out) {
  const int b   = blockIdx.x;
  const int tid = threadIdx.x;

  __shared__ double v[MM + 1];
  __shared__ double minv[MM + 1];
  __shared__ double u[NN + 1];
  __shared__ int    way[MM + 1];
  __shared__ int    p[MM + 1];
  __shared__ unsigned char used[MM + 1];
  __shared__ double redv[256];
  __shared__ int    redi[256];
  __shared__ int    s_j0;

  const double INFD = INFINITY;

  for (int j = tid; j <= MM; j += 256) { v[j] = 0.0; p[j] = 0; }
  for (int i = tid; i <= NN; i += 256) u[i] = 0.0;
  __syncthreads();

  for (int ii = 1; ii <= NN; ++ii) {
    if (tid == 0) { p[0] = ii; s_j0 = 0; }
    for (int j = tid; j <= MM; j += 256) { minv[j] = INFD; way[j] = 0; used[j] = 0; }
    __syncthreads();

    while (true) {
      const int j0 = s_j0;
      if (tid == 0) used[j0] = 1;
      const int i0 = p[j0];          // p stable inside while-loop
      const double ui0 = u[i0];      // u last written before previous barrier
      __syncthreads();               // used[j0] visible

      // scan free columns: update minv/way, local argmin (ascending j => first-index ties)
      double bestv = INFD;
      int    besti = MM + 1;
      for (int k = 0; k < 4; ++k) {
        const int j = 1 + tid + (k << 8);
        if (j <= MM && !used[j]) {
          const float cf = costT
              ? costT[(size_t)(b*NT + i0 - 1) * MM + (j - 1)]
              : C[((size_t)(b*NQ + (j - 1))) * SUMT + (b*NT + i0 - 1)];
          const double cur = ((double)cf - ui0) - v[j];
          if (cur < minv[j]) { minv[j] = cur; way[j] = j0; }
          const double mv = minv[j];
          if (mv < bestv) { bestv = mv; besti = j; }
        }
      }
      redv[tid] = bestv; redi[tid] = besti;
      __syncthreads();
      for (int s = 128; s > 0; s >>= 1) {
        if (tid < s) {
          const double ov = redv[tid + s]; const int oi = redi[tid + s];
          if (ov < redv[tid] || (ov == redv[tid] && oi < redi[tid])) {
            redv[tid] = ov; redi[tid] = oi;
          }
        }
        __syncthreads();
      }
      const int    j1    = redi[0];
      const double delta = redv[0];

      // dual updates (used cols' assigned rows are distinct -> no write conflicts)
      for (int j = tid; j <= MM; j += 256) {
        if (used[j]) { u[p[j]] += delta; v[j] -= delta; }
        else         { minv[j] -= delta; }
      }
      if (tid == 0) s_j0 = j1;
      __syncthreads();
      if (p[j1] == 0) break;         // uniform: p unchanged inside loop
    }

    // augment along the alternating path (serial, cheap)
    if (tid == 0) {
      int j0 = s_j0;
      while (j0) { const int j1 = way[j0]; p[j0] = p[j1]; j0 = j1; }
    }
    __syncthreads();
  }

  // emit pairs sorted by query index (j ascending == stable sort by row)
  if (tid == 0) {
    int k = 0;
    for (int j = 1; j <= MM; ++j) {
      if (p[j] > 0) {
        rows_out[b*NT + k] = (float)(j - 1);   // query index
        cols_out[b*NT + k] = (float)(p[j] - 1);// target index (image-local)
        ++k;
      }
    }
  }
}

extern "C" void kernel_launch(void* const* d_in, const int* in_sizes, int n_in,
                              void* d_out, int out_size, void* d_ws, size_t ws_size,
                              hipStream_t stream) {
  const float* logits = (const float*)d_in[0];
  const float* boxes  = (const float*)d_in[1];
  const int*   labels = (const int*)d_in[2];
  const float* tbox   = (const float*)d_in[3];

  float* C    = (float*)d_out;
  float* rows = C + (size_t)BSZ * NQ * SUMT;
  float* cols = rows + (size_t)BSZ * NT;

  float* costT = nullptr;
  const size_t needT = (size_t)SUMT * MM * sizeof(float);  // ~14.7 MB
  if (ws_size >= needT) costT = (float*)d_ws;

  hipLaunchKernelGGL(cost_kernel, dim3(BSZ * NQ), dim3(256), 0, stream,
                     logits, boxes, labels, tbox, C, costT);
  hipLaunchKernelGGL(lsa_kernel, dim3(BSZ), dim3(256), 0, stream,
                     C, costT, rows, cols);
}